// Round 1
// baseline (360.933 us; speedup 1.0000x reference)
//
#include <hip/hip_runtime.h>
#include <math.h>

// Problem dims (fixed by reference setup_inputs)
#define B_  8
#define D_  128
#define H_  256
#define W_  256
#define NACC 9      // S, SW, SW2, SD, SD2, SH, SH2, LEFT, CENT
#define NPART 256   // stage-1 blocks per batch

// central box bounds (D//3, 2D//3, etc.)
#define D1 42
#define D2 85
#define H1 85
#define H2 170
#define W1 85
#define W2 170

typedef float f32x4 __attribute__((ext_vector_type(4)));

__device__ __forceinline__ float waveSum(float x) {
    x += __shfl_down(x, 32, 64);
    x += __shfl_down(x, 16, 64);
    x += __shfl_down(x,  8, 64);
    x += __shfl_down(x,  4, 64);
    x += __shfl_down(x,  2, 64);
    x += __shfl_down(x,  1, 64);
    return x;
}

// Stage 1 streaming reduction.
// R1 lesson: no atomics (73728 contended RMWs cost ~550us serialized).
// R3 lesson: NOT latency-bound (4x MLP was neutral).
// R4 (this round): REVERT the nontemporal loads. NT never showed a measured
// win (331.6 -> 331.8), and the kernel streams at only ~1.7 TB/s despite
// perfect coalescing + sufficient MLP. Theory: `nt` bypasses L2 allocation,
// so the fabric services raw 64B requests (no 128B line-fill merging) and
// hits a request-rate cap, not the byte-BW cap. Plain cached dwordx4 loads
// take the m13-verified 6.3 TB/s streaming path; worst case they add back
// <=256 MB of dirty-ws LLC-eviction writebacks, still ~2x faster overall.
__global__ __launch_bounds__(256) void mfe_reduce(const float* __restrict__ in,
                                                  float* __restrict__ part) {
    const int b    = blockIdx.y;
    const int tid  = threadIdx.x;
    const int lane = tid & 63;
    const int wave = tid >> 6;
    const int gwave = blockIdx.x * 4 + wave;         // 0..1023

    const float* __restrict__ base = in + (size_t)b * (D_ * H_ * W_);

    // per-lane constants (w dimension)
    const int   w0  = lane * 4;
    const float fw0 = (float)(w0 + 0), fw1 = (float)(w0 + 1);
    const float fw2 = (float)(w0 + 2), fw3 = (float)(w0 + 3);
    const float q0 = fw0 * fw0, q1 = fw1 * fw1, q2 = fw2 * fw2, q3 = fw3 * fw3;
    const float cm0 = (w0 + 0 >= W1 && w0 + 0 < W2) ? 1.f : 0.f;
    const float cm1 = (w0 + 1 >= W1 && w0 + 1 < W2) ? 1.f : 0.f;
    const float cm2 = (w0 + 2 >= W1 && w0 + 2 < W2) ? 1.f : 0.f;
    const float cm3 = (w0 + 3 >= W1 && w0 + 3 < W2) ? 1.f : 0.f;
    const float lf  = (w0 < (W_ / 2)) ? 1.f : 0.f;   // lanes 0..31 cover w<128

    float aS = 0.f, aSW = 0.f, aSW2 = 0.f;
    float aSD = 0.f, aSD2 = 0.f, aSH = 0.f, aSH2 = 0.f;
    float aL = 0.f, aC = 0.f;

    // 32768 rows/batch, 1024 waves/batch, 4 consecutive rows per group,
    // 8 groups per wave (stride 4096 rows between groups).
    for (int g = 0; g < 8; ++g) {
        const int row0 = (gwave << 2) + (g << 12);   // 4*gwave + 4096*g
        const float* r = base + (size_t)row0 * W_ + w0;

        // 4 independent 16B cached loads in flight before any use
        const f32x4 p0 = *(const f32x4*)(r);
        const f32x4 p1 = *(const f32x4*)(r + W_);
        const f32x4 p2 = *(const f32x4*)(r + 2 * W_);
        const f32x4 p3 = *(const f32x4*)(r + 3 * W_);

        const int d  = row0 >> 8;                    // same d for all 4 rows
        const int h0 = row0 & (H_ - 1);              // h0, h0+1, h0+2, h0+3
        const float fd = (float)d;
        const bool dhit = (d >= D1 && d < D2);

#pragma unroll
        for (int j = 0; j < 4; ++j) {
            const f32x4 p = (j == 0) ? p0 : (j == 1) ? p1 : (j == 2) ? p2 : p3;
            const int   h  = h0 + j;
            const float fh = (float)h;

            const float s   = (p[0] + p[1]) + (p[2] + p[3]);
            const float sw  = fmaf(fw0, p[0], fmaf(fw1, p[1], fmaf(fw2, p[2], fw3 * p[3])));
            const float sw2 = fmaf(q0,  p[0], fmaf(q1,  p[1], fmaf(q2,  p[2], q3  * p[3])));
            const float cs  = fmaf(cm0, p[0], fmaf(cm1, p[1], fmaf(cm2, p[2], cm3 * p[3])));
            const float inbox = (dhit && h >= H1 && h < H2) ? 1.f : 0.f;

            aS   += s;
            aSW  += sw;
            aSW2 += sw2;
            aSD   = fmaf(fd,      s,  aSD);
            aSD2  = fmaf(fd * fd, s,  aSD2);
            aSH   = fmaf(fh,      s,  aSH);
            aSH2  = fmaf(fh * fh, s,  aSH2);
            aL    = fmaf(lf,      s,  aL);
            aC    = fmaf(inbox,   cs, aC);
        }
    }

    aS   = waveSum(aS);
    aSW  = waveSum(aSW);
    aSW2 = waveSum(aSW2);
    aSD  = waveSum(aSD);
    aSD2 = waveSum(aSD2);
    aSH  = waveSum(aSH);
    aSH2 = waveSum(aSH2);
    aL   = waveSum(aL);
    aC   = waveSum(aC);

    __shared__ float lds[4 * NACC];
    if (lane == 0) {
        float* l = lds + wave * NACC;
        l[0] = aS;  l[1] = aSW;  l[2] = aSW2;
        l[3] = aSD; l[4] = aSD2; l[5] = aSH; l[6] = aSH2;
        l[7] = aL;  l[8] = aC;
    }
    __syncthreads();
    if (tid < NACC) {
        const float v = lds[0 * NACC + tid] + lds[1 * NACC + tid]
                      + lds[2 * NACC + tid] + lds[3 * NACC + tid];
        part[((size_t)b * NPART + blockIdx.x) * NACC + tid] = v;
    }
}

// Stage 2: one wave per batch reduces NPART partial vectors and emits the
// 4 features.
__global__ __launch_bounds__(64) void mfe_final(const float* __restrict__ part,
                                                float* __restrict__ out) {
    const int b    = blockIdx.x;
    const int lane = threadIdx.x;
    const float* __restrict__ p = part + (size_t)b * NPART * NACC;

    float a[NACC];
#pragma unroll
    for (int k = 0; k < NACC; ++k) a[k] = 0.f;
    for (int r = lane; r < NPART; r += 64) {
#pragma unroll
        for (int k = 0; k < NACC; ++k) a[k] += p[r * NACC + k];
    }
#pragma unroll
    for (int k = 0; k < NACC; ++k) a[k] = waveSum(a[k]);

    if (lane == 0) {
        const float S = a[0], SW = a[1], SW2 = a[2];
        const float SD = a[3], SD2 = a[4], SH = a[5], SH2 = a[6];
        const float L = a[7], C = a[8];

        const float total = fmaxf(S, 1e-6f);
        const float md = SD / total, mh = SH / total, mw = SW / total;
        const float vd = SD2 / total - md * md;
        const float vh = SH2 / total - mh * mh;
        const float vw = SW2 / total - mw * mw;
        const float v  = fmaxf(fmaxf(fmaxf(vd, vh), vw), 0.f);

        const float diam_norm = fminf(fmaxf(2.f * sqrtf(v) * (1.0f / 100.0f), 0.f), 1.f);

        const float SPHERE_VOL = (4.0f / 3.0f) * 3.14159f * 1000.0f;   // 4188.78667
        const float count_norm = fminf(fmaxf(S / SPHERE_VOL, 0.f), 5.f) * (1.0f / 5.0f);

        const float vasc = fminf(fmaxf(C / total, 0.f), 1.f);

        const float R  = S - L;
        const float mn = fminf(L, R);
        const float mx = fmaxf(fmaxf(L, R), 1e-6f);
        const float lobe = fminf(fmaxf(mn / mx, 0.f), 1.f);

        out[b * 4 + 0] = diam_norm;
        out[b * 4 + 1] = count_norm;
        out[b * 4 + 2] = vasc;
        out[b * 4 + 3] = lobe;
    }
}

extern "C" void kernel_launch(void* const* d_in, const int* in_sizes, int n_in,
                              void* d_out, int out_size, void* d_ws, size_t ws_size,
                              hipStream_t stream) {
    const float* in   = (const float*)d_in[0];
    float*       out  = (float*)d_out;
    float*       part = (float*)d_ws;   // B_*NPART*NACC floats = 72 KB, fully
                                        // overwritten every launch (no memset).

    dim3 grid(NPART, B_);               // 2048 blocks, 8192 waves
    mfe_reduce<<<grid, 256, 0, stream>>>(in, part);
    mfe_final<<<B_, 64, 0, stream>>>(part, out);
}

// Round 2
// 352.082 us; speedup vs baseline: 1.0251x; 1.0251x over previous
//
#include <hip/hip_runtime.h>
#include <math.h>

// Problem dims (fixed by reference setup_inputs): B=8, D=128, H=256, W=256 fp32.
// Flat view: 2^23 elems/batch = 2^21 16B-chunks/batch, 2^24 chunks total.
#define B_    8
#define NACC  9          // S, SW, SW2, SD, SD2, SH, SH2, LEFT, CENT
#define NBLK  2048       // stage-1 blocks (256 thr) -> 8192 waves
#define NWAVE (NBLK * 4)
#define CPI   524288u    // chunks per grid sweep iteration = NBLK*256 threads

// central box bounds (D//3, 2D//3, etc.)
#define D1 42
#define D2 85
#define H1 85
#define H2 170
#define W1 85
#define W2 170

typedef float f32x4 __attribute__((ext_vector_type(4)));

__device__ __forceinline__ float waveSum(float x) {
    x += __shfl_down(x, 32, 64);
    x += __shfl_down(x, 16, 64);
    x += __shfl_down(x,  8, 64);
    x += __shfl_down(x,  4, 64);
    x += __shfl_down(x,  2, 64);
    x += __shfl_down(x,  1, 64);
    return x;
}

// Stage 1 streaming reduction.
// R1: no atomics (73728 contended RMWs ~550us). R3: not latency-bound (4x MLP
// neutral). R4: cached loads REGRESSED +29us vs NT (331.8 -> 360.9) -> NT kept;
// it avoids allocate/evict interference with the poison-filled LLC.
// R5 (this round): the old (b, 4-row-group, stride-4096) walk presents 8
// drifting 4MB frontiers = thousands of interleaved short read streams ->
// DRAM row-buffer thrash theory for the 1.7 TB/s (27% of ceiling) observed.
// Re-mapped to the m13-proven pattern: flat grid-strided linear sweep, whole
// GPU inside one contiguous 8MB moving window. Batch index is uniform per
// sweep iteration (b = i>>2), so per-batch accumulators flush every 4 iters.
__global__ __launch_bounds__(256) void mfe_reduce(const float* __restrict__ in,
                                                  float* __restrict__ part) {
    const int tid  = threadIdx.x;
    const int lane = tid & 63;
    const int gtid = blockIdx.x * 256 + tid;           // 0..524287
    const int gw   = (blockIdx.x << 2) + (tid >> 6);   // global wave 0..8191

    // per-lane W-dimension constants: w0 = (c & 63)*4 depends only on gtid
    const int   w0  = (gtid & 63) << 2;
    const float fw0 = (float)(w0 + 0), fw1 = (float)(w0 + 1);
    const float fw2 = (float)(w0 + 2), fw3 = (float)(w0 + 3);
    const float q0 = fw0 * fw0, q1 = fw1 * fw1, q2 = fw2 * fw2, q3 = fw3 * fw3;
    const float cm0 = (w0 + 0 >= W1 && w0 + 0 < W2) ? 1.f : 0.f;
    const float cm1 = (w0 + 1 >= W1 && w0 + 1 < W2) ? 1.f : 0.f;
    const float cm2 = (w0 + 2 >= W1 && w0 + 2 < W2) ? 1.f : 0.f;
    const float cm3 = (w0 + 3 >= W1 && w0 + 3 < W2) ? 1.f : 0.f;
    const float lf  = (w0 < 128) ? 1.f : 0.f;

    const f32x4* __restrict__ cin = (const f32x4*)in;

    for (int ib = 0; ib < B_; ++ib) {
        // 4 sweep iterations cover exactly batch ib; 4 independent NT loads
        // 8 MiB apart, all issued before any use.
        const unsigned c0 = (unsigned)(ib * 4) * CPI + (unsigned)gtid;
        const f32x4 p0 = __builtin_nontemporal_load(cin + c0);
        const f32x4 p1 = __builtin_nontemporal_load(cin + c0 + CPI);
        const f32x4 p2 = __builtin_nontemporal_load(cin + c0 + 2 * CPI);
        const f32x4 p3 = __builtin_nontemporal_load(cin + c0 + 3 * CPI);

        float aS = 0.f, aSW = 0.f, aSW2 = 0.f;
        float aSD = 0.f, aSD2 = 0.f, aSH = 0.f, aSH2 = 0.f;
        float aL = 0.f, aC = 0.f;

#pragma unroll
        for (int j = 0; j < 4; ++j) {
            const f32x4 p = (j == 0) ? p0 : (j == 1) ? p1 : (j == 2) ? p2 : p3;
            const unsigned c = c0 + (unsigned)j * CPI;
            const int d = (int)((c >> 14) & 127);
            const int h = (int)((c >> 6) & 255);
            const float fd = (float)d, fh = (float)h;

            const float s   = (p[0] + p[1]) + (p[2] + p[3]);
            const float sw  = fmaf(fw0, p[0], fmaf(fw1, p[1], fmaf(fw2, p[2], fw3 * p[3])));
            const float sw2 = fmaf(q0,  p[0], fmaf(q1,  p[1], fmaf(q2,  p[2], q3  * p[3])));
            const float cs  = fmaf(cm0, p[0], fmaf(cm1, p[1], fmaf(cm2, p[2], cm3 * p[3])));
            const float inbox = (d >= D1 && d < D2 && h >= H1 && h < H2) ? 1.f : 0.f;

            aS   += s;
            aSW  += sw;
            aSW2 += sw2;
            aSD   = fmaf(fd,      s,  aSD);
            aSD2  = fmaf(fd * fd, s,  aSD2);
            aSH   = fmaf(fh,      s,  aSH);
            aSH2  = fmaf(fh * fh, s,  aSH2);
            aL    = fmaf(lf,      s,  aL);
            aC    = fmaf(inbox,   cs, aC);
        }

        aS   = waveSum(aS);
        aSW  = waveSum(aSW);
        aSW2 = waveSum(aSW2);
        aSD  = waveSum(aSD);
        aSD2 = waveSum(aSD2);
        aSH  = waveSum(aSH);
        aSH2 = waveSum(aSH2);
        aL   = waveSum(aL);
        aC   = waveSum(aC);

        if (lane == 0) {
            float* o = part + ((size_t)ib * NWAVE + gw) * NACC;
            o[0] = aS;  o[1] = aSW;  o[2] = aSW2;
            o[3] = aSD; o[4] = aSD2; o[5] = aSH; o[6] = aSH2;
            o[7] = aL;  o[8] = aC;
        }
    }
}

// Stage 2: one 256-thread block per batch reduces NWAVE partial vectors
// (8192 x 9 floats = 288 KB/batch) and emits the 4 features.
__global__ __launch_bounds__(256) void mfe_final(const float* __restrict__ part,
                                                 float* __restrict__ out) {
    const int b    = blockIdx.x;
    const int tid  = threadIdx.x;
    const int lane = tid & 63;
    const int wave = tid >> 6;
    const float* __restrict__ p = part + (size_t)b * NWAVE * NACC;

    float a[NACC];
#pragma unroll
    for (int k = 0; k < NACC; ++k) a[k] = 0.f;
    for (int r = tid; r < NWAVE; r += 256) {
#pragma unroll
        for (int k = 0; k < NACC; ++k) a[k] += p[r * NACC + k];
    }
#pragma unroll
    for (int k = 0; k < NACC; ++k) a[k] = waveSum(a[k]);

    __shared__ float lds[4 * NACC];
    if (lane == 0) {
#pragma unroll
        for (int k = 0; k < NACC; ++k) lds[wave * NACC + k] = a[k];
    }
    __syncthreads();

    if (tid == 0) {
        float t[NACC];
#pragma unroll
        for (int k = 0; k < NACC; ++k)
            t[k] = lds[0 * NACC + k] + lds[1 * NACC + k]
                 + lds[2 * NACC + k] + lds[3 * NACC + k];

        const float S = t[0], SW = t[1], SW2 = t[2];
        const float SD = t[3], SD2 = t[4], SH = t[5], SH2 = t[6];
        const float L = t[7], C = t[8];

        const float total = fmaxf(S, 1e-6f);
        const float md = SD / total, mh = SH / total, mw = SW / total;
        const float vd = SD2 / total - md * md;
        const float vh = SH2 / total - mh * mh;
        const float vw = SW2 / total - mw * mw;
        const float v  = fmaxf(fmaxf(fmaxf(vd, vh), vw), 0.f);

        const float diam_norm = fminf(fmaxf(2.f * sqrtf(v) * (1.0f / 100.0f), 0.f), 1.f);

        const float SPHERE_VOL = (4.0f / 3.0f) * 3.14159f * 1000.0f;   // 4188.78667
        const float count_norm = fminf(fmaxf(S / SPHERE_VOL, 0.f), 5.f) * (1.0f / 5.0f);

        const float vasc = fminf(fmaxf(C / total, 0.f), 1.f);

        const float R  = S - L;
        const float mn = fminf(L, R);
        const float mx = fmaxf(fmaxf(L, R), 1e-6f);
        const float lobe = fminf(fmaxf(mn / mx, 0.f), 1.f);

        out[b * 4 + 0] = diam_norm;
        out[b * 4 + 1] = count_norm;
        out[b * 4 + 2] = vasc;
        out[b * 4 + 3] = lobe;
    }
}

extern "C" void kernel_launch(void* const* d_in, const int* in_sizes, int n_in,
                              void* d_out, int out_size, void* d_ws, size_t ws_size,
                              hipStream_t stream) {
    const float* in   = (const float*)d_in[0];
    float*       out  = (float*)d_out;
    float*       part = (float*)d_ws;   // B_*NWAVE*NACC floats = 2.36 MB, fully
                                        // overwritten every launch (no memset).

    mfe_reduce<<<NBLK, 256, 0, stream>>>(in, part);
    mfe_final<<<B_, 256, 0, stream>>>(part, out);
}